// Round 12
// baseline (167.303 us; speedup 1.0000x reference)
//
#include <hip/hip_runtime.h>
#include <math.h>

#define S_LEN 2048
#define NB 4
#define EMB 1024
#define HD 64
#define NROW (NB * S_LEN)
#define NEG_BIG -3.0e38f
#define SC 11.5415603f /* 8 * log2(e) */
#define DEFER_THR 3.0f
#define KVSPLIT 4

typedef _Float16 half8 __attribute__((ext_vector_type(8)));
typedef _Float16 half4 __attribute__((ext_vector_type(4)));
typedef float f32x4 __attribute__((ext_vector_type(4)));

static __device__ __forceinline__ f32x4 mfma32(half8 a, half8 b, f32x4 c) {
    return __builtin_amdgcn_mfma_f32_16x16x32_f16(a, b, c, 0, 0, 0);
}
// K=16 shape: A-frag k-index = (lane>>4)*4 + i (validated empirically R4-R11).
static __device__ __forceinline__ f32x4 mfma16(half4 a, half4 b, f32x4 c) {
    return __builtin_amdgcn_mfma_f32_16x16x16f16(a, b, c, 0, 0, 0);
}

// ---------------------------------------------------------------------------
// prep_w: W [1024][64] fp32 -> W^T fp16 in MFMA-FRAGMENT-LINEAR layout:
//   addr = f*16384 + c32*512 + lane*8 + e
//   value = W^T[f*16 + (lane&15)][c32*32 + (lane>>4)*8 + e]
// grid 48 (3 mats x 16 k-chunks of 64), 256 thr, coalesced in.  (R9 exact)
// ---------------------------------------------------------------------------
__global__ __launch_bounds__(256) void prep_w(
    const float* __restrict__ Wq, const float* __restrict__ Wk,
    const float* __restrict__ Wv, _Float16* __restrict__ wt_frag)
{
    const int g  = blockIdx.x >> 4;
    const int kc = blockIdx.x & 15;          // 64-k chunk
    const int k0 = kc * 64;
    const float* W = (g == 0) ? Wq : (g == 1) ? Wk : Wv;

    __shared__ float tile[64][68];
    const int t = threadIdx.x;
    {
        const int kk = t >> 2, cb = (t & 3) * 16;
#pragma unroll
        for (int i = 0; i < 4; i++)
            *(f32x4*)&tile[kk][cb + 4 * i] =
                *(const f32x4*)(W + (size_t)(k0 + kk) * HD + cb + 4 * i);
    }
    __syncthreads();

    const int c4 = t >> 6, l = t & 63;
    const int col = c4 * 16 + (l & 15);
    const int krow = (l >> 4) * 8;
#pragma unroll
    for (int sub = 0; sub < 2; sub++) {
        half8 hv;
#pragma unroll
        for (int e = 0; e < 8; e++)
            hv[e] = (_Float16)tile[sub * 32 + krow + e][col];
        const size_t addr = (size_t)(g * 4 + c4) * 16384 +
                            (size_t)(kc * 2 + sub) * 512 + (size_t)l * 8;
        *(half8*)(wt_frag + addr) = hv;
    }
}

// ---------------------------------------------------------------------------
// proj_kernel: fused q,k,v projection.  256 blocks x 768 thr (12 waves).
// x strip (32x1024) staged to LDS ONCE; W^T streamed per-wave from global in
// fragment-linear layout (contiguous 1KB/load), 4-deep register prefetch.
// K-loop BARRIER-FREE.  (R9 exact -- near HBM floor)
// ---------------------------------------------------------------------------
__global__ __launch_bounds__(768) void proj_kernel(
    const float* __restrict__ x, const _Float16* __restrict__ wt_frag,
    const float* __restrict__ bq, const float* __restrict__ bk,
    const float* __restrict__ bv,
    _Float16* __restrict__ qs, _Float16* __restrict__ kh_,
    _Float16* __restrict__ vt)
{
    const int m0 = blockIdx.x * 32;
    const int t = threadIdx.x, lane = t & 63, w = t >> 6;   // w 0..11

    __shared__ __align__(16) _Float16 xs[32][1032];

    // ---- stage x strip once: 32 rows x 1024 f32 -> fp16 ----
    for (int i = t; i < 4096; i += 768) {
        const int row = i >> 7, off = (i & 127) * 8;
        const float* xp = x + (size_t)(m0 + row) * EMB + off;
        const f32x4 v0 = *(const f32x4*)xp;
        const f32x4 v1 = *(const f32x4*)(xp + 4);
        half8 h;
#pragma unroll
        for (int jj = 0; jj < 4; jj++) {
            h[jj]     = (_Float16)v0[jj];
            h[4 + jj] = (_Float16)v1[jj];
        }
        *(half8*)&xs[row][off] = h;
    }

    const int f = w;
    const int row0 = lane & 15, kq = lane >> 4;
    const _Float16* wp = wt_frag + (size_t)f * 16384 + (size_t)lane * 8;

    half8 wbuf[4];
#pragma unroll
    for (int c = 0; c < 4; c++) wbuf[c] = *(const half8*)(wp + (size_t)c * 512);

    __syncthreads();

    f32x4 acc0 = f32x4{0, 0, 0, 0}, acc1 = f32x4{0, 0, 0, 0};

#pragma unroll
    for (int c = 0; c < 32; ++c) {
        const half8 ax0 = *(const half8*)&xs[row0][c * 32 + kq * 8];
        const half8 ax1 = *(const half8*)&xs[16 + row0][c * 32 + kq * 8];
        const half8 bw = wbuf[c & 3];
        acc0 = mfma32(ax0, bw, acc0);
        acc1 = mfma32(ax1, bw, acc1);
        if (c + 4 < 32) wbuf[c & 3] = *(const half8*)(wp + (size_t)(c + 4) * 512);
    }

    // ---- epilogue ----
    const int mat = f >> 2, c4 = f & 3;
    const int mcol = c4 * 16 + (lane & 15);
    const float bb = ((mat == 0) ? bq : (mat == 1) ? bk : bv)[mcol];
#pragma unroll
    for (int rh = 0; rh < 2; rh++) {
        const f32x4 acc = rh ? acc1 : acc0;
        const int grow0 = m0 + rh * 16 + kq * 4;
        if (mat == 0) {
#pragma unroll
            for (int r = 0; r < 4; r++)
                qs[(size_t)(grow0 + r) * HD + mcol] = (_Float16)((acc[r] + bb) * SC);
        } else if (mat == 1) {
#pragma unroll
            for (int r = 0; r < 4; r++)
                kh_[(size_t)(grow0 + r) * HD + mcol] = (_Float16)(acc[r] + bb);
        } else {
            half4 hv;
#pragma unroll
            for (int r = 0; r < 4; r++) hv[r] = (_Float16)(acc[r] + bb);
            const int bidx = grow0 >> 11, sr = grow0 & (S_LEN - 1);
            *(half4*)(vt + ((size_t)bidx * HD + mcol) * S_LEN + sr) = hv;
        }
    }
}

// ---------------------------------------------------------------------------
// attn_kernel: causal flash attention, swapped-QK, DOUBLE-BUFFERED LDS K/V
// tiles -> ONE barrier per tile-step.  512 blocks (32 q-tiles of 64 x
// 4 batch x KVSPLIT=4) x 512 thr.  (R9 loop verbatim)
// NEW: split-K merge FUSED via last-block atomic ticket (threadfence release
// -> atomicAdd -> last block threadfence acquire + merge + write out).
// ---------------------------------------------------------------------------
__global__ __launch_bounds__(512) void attn_kernel(
    const _Float16* __restrict__ qs, const _Float16* __restrict__ kh_,
    const _Float16* __restrict__ vt,
    _Float16* __restrict__ po, float* __restrict__ pm, float* __restrict__ pl,
    float* __restrict__ out, int* __restrict__ cnt)
{
    const int id = blockIdx.x;
    const int qq = id & 3;
    const int b  = (id >> 2) & 3;
    const int qt = 31 - (id >> 4);            // biggest q-tiles first
    const int q0 = qt * 64;
    const int t = threadIdx.x, lane = t & 63, w = t >> 6;
    const int rf = w >> 1, kvh = w & 1;

    __shared__ __align__(16) unsigned char smem[37888];
    _Float16 (*klds)[64][72] = (_Float16(*)[64][72])smem;          // [2][64][72]
    _Float16 (*vlds)[64][72] = (_Float16(*)[64][72])(smem + 18432);// [2][64][72]
    float (*obuf)[16][68] = (float(*)[16][68])smem;                // alias, post-loop
    float* mbuf = (float*)(smem + 36864);                          // [8][16]
    float* lbuf = (float*)(smem + 36864 + 512);                    // [8][16]
    __shared__ int lastFlag;

    const size_t rowq = ((size_t)b * S_LEN + q0 + rf * 16 + (lane & 15)) * HD + (lane >> 4) * 8;
    const half8 bq0 = *(const half8*)(qs + rowq);
    const half8 bq1 = *(const half8*)(qs + rowq + 32);

    f32x4 o[4];
#pragma unroll
    for (int c = 0; c < 4; c++) o[c] = f32x4{0, 0, 0, 0};
    float m_r = NEG_BIG, l_r = 0.f;

    const int nt = qt + 1;
    const int lo = (nt * qq) >> 2, hi = (nt * (qq + 1)) >> 2;

    const size_t kbase = (size_t)b * S_LEN * HD;
    const size_t vbase = (size_t)b * HD * S_LEN;
    const int srow = t >> 3, scol = (t & 7) * 8;

    half8 sK, sV;
    auto gload = [&](int tl) {
        sK = *(const half8*)(kh_ + kbase + (size_t)(tl * 64 + srow) * HD + scol);
        sV = *(const half8*)(vt + vbase + (size_t)srow * S_LEN + tl * 64 + scol);
    };
    auto swrite = [&](int nb) {
        *(half8*)&klds[nb][srow][scol] = sK;
        *(half8*)&vlds[nb][srow][scol] = sV;
    };

    if (lo < hi) { gload(lo); swrite(0); }
    __syncthreads();

    int cur = 0;
    for (int tl = lo; tl < hi; ++tl) {
        if (tl + 1 < hi) gload(tl + 1);       // issue next tile early

        const int kv0 = tl * 64 + kvh * 32;
        __builtin_amdgcn_s_setprio(1);
        f32x4 s[2];
#pragma unroll
        for (int h = 0; h < 2; h++) {
            const int keyl = kvh * 32 + 16 * h + (lane & 15);
            f32x4 a = f32x4{0, 0, 0, 0};
            a = mfma32(*(const half8*)&klds[cur][keyl][(lane >> 4) * 8], bq0, a);
            a = mfma32(*(const half8*)&klds[cur][keyl][32 + (lane >> 4) * 8], bq1, a);
            s[h] = a;
        }
        __builtin_amdgcn_s_setprio(0);

        const int qrow = q0 + rf * 16 + (lane & 15);
        const int kb0  = kv0 + (lane >> 4) * 4;
        float tv[8];
#pragma unroll
        for (int h = 0; h < 2; h++)
#pragma unroll
            for (int r = 0; r < 4; r++)
                tv[h * 4 + r] = (kb0 + 16 * h + r <= qrow) ? s[h][r] : NEG_BIG;

        float mt = tv[0];
#pragma unroll
        for (int i = 1; i < 8; i++) mt = fmaxf(mt, tv[i]);
        mt = fmaxf(mt, __shfl_xor(mt, 16));
        mt = fmaxf(mt, __shfl_xor(mt, 32));

        if (!__all(mt <= m_r + DEFER_THR)) {  // defer-max rescale
            const float mn = fmaxf(m_r, mt);
            const float corr = exp2f(m_r - mn);
            m_r = mn;
            l_r *= corr;
            float corrB[4];
#pragma unroll
            for (int r = 0; r < 4; r++) corrB[r] = __shfl(corr, (lane >> 4) * 4 + r);
#pragma unroll
            for (int c = 0; c < 4; c++)
#pragma unroll
                for (int r = 0; r < 4; r++) o[c][r] *= corrB[r];
        }

        float p[8], rs = 0.f;
#pragma unroll
        for (int i = 0; i < 8; i++) { p[i] = exp2f(tv[i] - m_r); rs += p[i]; }
        rs += __shfl_xor(rs, 16);
        rs += __shfl_xor(rs, 32);
        l_r += rs;

        half4 pa[2];
#pragma unroll
        for (int h = 0; h < 2; h++)
#pragma unroll
            for (int r = 0; r < 4; r++) pa[h][r] = (_Float16)p[h * 4 + r];
        __builtin_amdgcn_s_setprio(1);
#pragma unroll
        for (int c = 0; c < 4; c++) {
#pragma unroll
            for (int h = 0; h < 2; h++) {
                const half4 vf = *(const half4*)&vlds[cur][16 * c + (lane & 15)]
                                                    [kvh * 32 + 16 * h + (lane >> 4) * 4];
                o[c] = mfma16(pa[h], vf, o[c]);
            }
        }
        __builtin_amdgcn_s_setprio(0);

        if (tl + 1 < hi) swrite(cur ^ 1);     // write OTHER buffer (race-free)
        __syncthreads();                      // single barrier per tile
        cur ^= 1;
    }

    // ---- pairwise (kv-half) merge, write block partial ----
    if (lane < 16) { mbuf[w * 16 + lane] = m_r; lbuf[w * 16 + lane] = l_r; }
#pragma unroll
    for (int c = 0; c < 4; c++)
#pragma unroll
        for (int r = 0; r < 4; r++)
            obuf[w][(lane >> 4) * 4 + r][16 * c + (lane & 15)] = o[c][r];
    __syncthreads();

    if (t < 256) {
        const int row16 = t >> 4, cb = (t & 15) * 4;
#pragma unroll
        for (int rf2 = 0; rf2 < 4; rf2++) {
            const int w0 = rf2 * 2, w1 = w0 + 1;
            const float m0v = mbuf[w0 * 16 + row16], m1v = mbuf[w1 * 16 + row16];
            const float M = fmaxf(m0v, m1v);
            const float e0 = exp2f(m0v - M), e1 = exp2f(m1v - M);
            const float L = lbuf[w0 * 16 + row16] * e0 + lbuf[w1 * 16 + row16] * e1;
            const f32x4 o0 = *(const f32x4*)&obuf[w0][row16][cb];
            const f32x4 o1 = *(const f32x4*)&obuf[w1][row16][cb];
            half4 hv;
#pragma unroll
            for (int jj = 0; jj < 4; jj++) hv[jj] = (_Float16)(o0[jj] * e0 + o1[jj] * e1);
            const size_t idx = (size_t)(qq * NB + b) * S_LEN + q0 + rf2 * 16 + row16;
            *(half4*)(po + idx * HD + cb) = hv;
            if ((t & 15) == 0) { pm[idx] = M; pl[idx] = L; }
        }
    }

    // ---- last-block ticket: fuse the KVSPLIT merge ----
    __threadfence();                          // release partials device-wide
    __syncthreads();                          // all stores+fences before ticket
    if (t == 0) {
        const int old = atomicAdd(&cnt[qt * NB + b], 1);
        lastFlag = (old == KVSPLIT - 1) ? 1 : 0;
    }
    __syncthreads();
    if (!lastFlag) return;
    __threadfence();                          // acquire other blocks' partials

    {
        const int row = t >> 3;               // 0..63
        const int cb  = (t & 7) * 8;          // 0..56
        const int grow = q0 + row;
        float mv[KVSPLIT], M = NEG_BIG;
#pragma unroll
        for (int q2 = 0; q2 < KVSPLIT; q2++) {
            mv[q2] = pm[(size_t)(q2 * NB + b) * S_LEN + grow];
            M = fmaxf(M, mv[q2]);
        }
        float L = 0.f;
        float acc[8] = {0, 0, 0, 0, 0, 0, 0, 0};
#pragma unroll
        for (int q2 = 0; q2 < KVSPLIT; q2++) {
            const size_t idx = (size_t)(q2 * NB + b) * S_LEN + grow;
            const float e = exp2f(mv[q2] - M);
            L += pl[idx] * e;
            const half8 ov = *(const half8*)(po + idx * HD + cb);
#pragma unroll
            for (int jj = 0; jj < 8; jj++) acc[jj] += (float)ov[jj] * e;
        }
        const float inv = 1.0f / L;
        f32x4 r0, r1;
#pragma unroll
        for (int jj = 0; jj < 4; jj++) { r0[jj] = acc[jj] * inv; r1[jj] = acc[4 + jj] * inv; }
        float* op = out + ((size_t)b * S_LEN + grow) * HD + cb;
        *(f32x4*)op = r0;
        *(f32x4*)(op + 4) = r1;
    }
}

extern "C" void kernel_launch(void* const* d_in, const int* in_sizes, int n_in,
                              void* d_out, int out_size, void* d_ws, size_t ws_size,
                              hipStream_t stream) {
    const float* x  = (const float*)d_in[0];
    const float* Wq = (const float*)d_in[1];
    const float* bq = (const float*)d_in[2];
    const float* Wk = (const float*)d_in[3];
    const float* bk = (const float*)d_in[4];
    const float* Wv = (const float*)d_in[5];
    const float* bv = (const float*)d_in[6];
    float* out = (float*)d_out;

    _Float16* ws = (_Float16*)d_ws;
    const size_t nW = (size_t)192 * EMB;     // 196608 (12 frags x 16384)
    const size_t n  = (size_t)NROW * HD;     // 524288
    _Float16* wt_frag = ws;
    _Float16* qsb = wt_frag + nW;
    _Float16* khb = qsb + n;
    _Float16* vtb = khb + n;
    _Float16* po = vtb + n;                                // [4][4][2048][64] fp16
    float* pm = (float*)(po + (size_t)KVSPLIT * NB * S_LEN * HD);  // [4][4][2048]
    float* pl = pm + (size_t)KVSPLIT * NB * S_LEN;
    int* cnt = (int*)(pl + (size_t)KVSPLIT * NB * S_LEN); // [32*NB]

    hipMemsetAsync(cnt, 0, 32 * NB * sizeof(int), stream);
    prep_w<<<48, 256, 0, stream>>>(Wq, Wk, Wv, wt_frag);
    proj_kernel<<<NROW / 32, 768, 0, stream>>>(
        x, wt_frag, bq, bk, bv, qsb, khb, vtb);
    attn_kernel<<<32 * NB * KVSPLIT, 512, 0, stream>>>(
        qsb, khb, vtb, po, pm, pl, out, cnt);
}

// Round 13
// 36.832 us; speedup vs baseline: 4.5423x; 4.5423x over previous
//
#include <hip/hip_runtime.h>
#include <math.h>

#define S_LEN 2048
#define NB 4
#define EMB 1024
#define HD 64
#define NROW (NB * S_LEN)
#define NEG_BIG -3.0e38f
#define SC 11.5415603f /* 8 * log2(e) */
#define DEFER_THR 3.0f
#define KVSPLIT 4

typedef _Float16 half8 __attribute__((ext_vector_type(8)));
typedef _Float16 half4 __attribute__((ext_vector_type(4)));
typedef float f32x4 __attribute__((ext_vector_type(4)));

static __device__ __forceinline__ f32x4 mfma32(half8 a, half8 b, f32x4 c) {
    return __builtin_amdgcn_mfma_f32_16x16x32_f16(a, b, c, 0, 0, 0);
}
// K=16 shape: A-frag k-index = (lane>>4)*4 + i (validated empirically R4-R12).
static __device__ __forceinline__ f32x4 mfma16(half4 a, half4 b, f32x4 c) {
    return __builtin_amdgcn_mfma_f32_16x16x16f16(a, b, c, 0, 0, 0);
}

// ---------------------------------------------------------------------------
// prep_w: W [1024][64] fp32 -> W^T fp16 in MFMA-FRAGMENT-LINEAR layout:
//   addr = f*16384 + c32*512 + lane*8 + e
//   value = W^T[f*16 + (lane&15)][c32*32 + (lane>>4)*8 + e]
// grid 48 (3 mats x 16 k-chunks of 64), 256 thr, coalesced in.  (R9 exact)
// ---------------------------------------------------------------------------
__global__ __launch_bounds__(256) void prep_w(
    const float* __restrict__ Wq, const float* __restrict__ Wk,
    const float* __restrict__ Wv, _Float16* __restrict__ wt_frag)
{
    const int g  = blockIdx.x >> 4;
    const int kc = blockIdx.x & 15;          // 64-k chunk
    const int k0 = kc * 64;
    const float* W = (g == 0) ? Wq : (g == 1) ? Wk : Wv;

    __shared__ float tile[64][68];
    const int t = threadIdx.x;
    {
        const int kk = t >> 2, cb = (t & 3) * 16;
#pragma unroll
        for (int i = 0; i < 4; i++)
            *(f32x4*)&tile[kk][cb + 4 * i] =
                *(const f32x4*)(W + (size_t)(k0 + kk) * HD + cb + 4 * i);
    }
    __syncthreads();

    const int c4 = t >> 6, l = t & 63;
    const int col = c4 * 16 + (l & 15);
    const int krow = (l >> 4) * 8;
#pragma unroll
    for (int sub = 0; sub < 2; sub++) {
        half8 hv;
#pragma unroll
        for (int e = 0; e < 8; e++)
            hv[e] = (_Float16)tile[sub * 32 + krow + e][col];
        const size_t addr = (size_t)(g * 4 + c4) * 16384 +
                            (size_t)(kc * 2 + sub) * 512 + (size_t)l * 8;
        *(half8*)(wt_frag + addr) = hv;
    }
}

// ---------------------------------------------------------------------------
// proj_kernel: fused q,k,v projection.  256 blocks x 768 thr (12 waves).
// x strip (32x1024) staged to LDS ONCE; W^T streamed per-wave from global in
// fragment-linear layout (contiguous 1KB/load), 4-deep register prefetch.
// K-loop BARRIER-FREE.  (R9 exact -- near HBM floor)
// ---------------------------------------------------------------------------
__global__ __launch_bounds__(768) void proj_kernel(
    const float* __restrict__ x, const _Float16* __restrict__ wt_frag,
    const float* __restrict__ bq, const float* __restrict__ bk,
    const float* __restrict__ bv,
    _Float16* __restrict__ qs, _Float16* __restrict__ kh_,
    _Float16* __restrict__ vt)
{
    const int m0 = blockIdx.x * 32;
    const int t = threadIdx.x, lane = t & 63, w = t >> 6;   // w 0..11

    __shared__ __align__(16) _Float16 xs[32][1032];

    // ---- stage x strip once: 32 rows x 1024 f32 -> fp16 ----
    for (int i = t; i < 4096; i += 768) {
        const int row = i >> 7, off = (i & 127) * 8;
        const float* xp = x + (size_t)(m0 + row) * EMB + off;
        const f32x4 v0 = *(const f32x4*)xp;
        const f32x4 v1 = *(const f32x4*)(xp + 4);
        half8 h;
#pragma unroll
        for (int jj = 0; jj < 4; jj++) {
            h[jj]     = (_Float16)v0[jj];
            h[4 + jj] = (_Float16)v1[jj];
        }
        *(half8*)&xs[row][off] = h;
    }

    const int f = w;
    const int row0 = lane & 15, kq = lane >> 4;
    const _Float16* wp = wt_frag + (size_t)f * 16384 + (size_t)lane * 8;

    half8 wbuf[4];
#pragma unroll
    for (int c = 0; c < 4; c++) wbuf[c] = *(const half8*)(wp + (size_t)c * 512);

    __syncthreads();

    f32x4 acc0 = f32x4{0, 0, 0, 0}, acc1 = f32x4{0, 0, 0, 0};

#pragma unroll
    for (int c = 0; c < 32; ++c) {
        const half8 ax0 = *(const half8*)&xs[row0][c * 32 + kq * 8];
        const half8 ax1 = *(const half8*)&xs[16 + row0][c * 32 + kq * 8];
        const half8 bw = wbuf[c & 3];
        acc0 = mfma32(ax0, bw, acc0);
        acc1 = mfma32(ax1, bw, acc1);
        if (c + 4 < 32) wbuf[c & 3] = *(const half8*)(wp + (size_t)(c + 4) * 512);
    }

    // ---- epilogue ----
    const int mat = f >> 2, c4 = f & 3;
    const int mcol = c4 * 16 + (lane & 15);
    const float bb = ((mat == 0) ? bq : (mat == 1) ? bk : bv)[mcol];
#pragma unroll
    for (int rh = 0; rh < 2; rh++) {
        const f32x4 acc = rh ? acc1 : acc0;
        const int grow0 = m0 + rh * 16 + kq * 4;
        if (mat == 0) {
#pragma unroll
            for (int r = 0; r < 4; r++)
                qs[(size_t)(grow0 + r) * HD + mcol] = (_Float16)((acc[r] + bb) * SC);
        } else if (mat == 1) {
#pragma unroll
            for (int r = 0; r < 4; r++)
                kh_[(size_t)(grow0 + r) * HD + mcol] = (_Float16)(acc[r] + bb);
        } else {
            half4 hv;
#pragma unroll
            for (int r = 0; r < 4; r++) hv[r] = (_Float16)(acc[r] + bb);
            const int bidx = grow0 >> 11, sr = grow0 & (S_LEN - 1);
            *(half4*)(vt + ((size_t)bidx * HD + mcol) * S_LEN + sr) = hv;
        }
    }
}

// ---------------------------------------------------------------------------
// attn_kernel: causal flash attention, swapped-QK, DOUBLE-BUFFERED LDS K/V
// tiles -> ONE barrier per tile-step.  512 blocks (32 q-tiles of 64 x
// 4 batch x KVSPLIT=4) x 512 thr.  (R9 structure; separate merge kernel.)
// NEW vs R9: wave-uniform unmasked-tile fast path skips the 8 cmp+cndmask
// mask ops on interior tiles (~3 of 4 tile-steps per wave).
// ---------------------------------------------------------------------------
__global__ __launch_bounds__(512) void attn_kernel(
    const _Float16* __restrict__ qs, const _Float16* __restrict__ kh_,
    const _Float16* __restrict__ vt,
    _Float16* __restrict__ po, float* __restrict__ pm, float* __restrict__ pl)
{
    const int id = blockIdx.x;
    const int qq = id & 3;
    const int b  = (id >> 2) & 3;
    const int qt = 31 - (id >> 4);            // biggest q-tiles first
    const int q0 = qt * 64;
    const int t = threadIdx.x, lane = t & 63, w = t >> 6;
    const int rf = w >> 1, kvh = w & 1;

    __shared__ __align__(16) unsigned char smem[37888];
    _Float16 (*klds)[64][72] = (_Float16(*)[64][72])smem;          // [2][64][72]
    _Float16 (*vlds)[64][72] = (_Float16(*)[64][72])(smem + 18432);// [2][64][72]
    float (*obuf)[16][68] = (float(*)[16][68])smem;                // alias, post-loop
    float* mbuf = (float*)(smem + 36864);                          // [8][16]
    float* lbuf = (float*)(smem + 36864 + 512);                    // [8][16]

    const size_t rowq = ((size_t)b * S_LEN + q0 + rf * 16 + (lane & 15)) * HD + (lane >> 4) * 8;
    const half8 bq0 = *(const half8*)(qs + rowq);
    const half8 bq1 = *(const half8*)(qs + rowq + 32);

    f32x4 o[4];
#pragma unroll
    for (int c = 0; c < 4; c++) o[c] = f32x4{0, 0, 0, 0};
    float m_r = NEG_BIG, l_r = 0.f;

    const int nt = qt + 1;
    const int lo = (nt * qq) >> 2, hi = (nt * (qq + 1)) >> 2;

    const size_t kbase = (size_t)b * S_LEN * HD;
    const size_t vbase = (size_t)b * HD * S_LEN;
    const int srow = t >> 3, scol = (t & 7) * 8;

    half8 sK, sV;
    auto gload = [&](int tl) {
        sK = *(const half8*)(kh_ + kbase + (size_t)(tl * 64 + srow) * HD + scol);
        sV = *(const half8*)(vt + vbase + (size_t)srow * S_LEN + tl * 64 + scol);
    };
    auto swrite = [&](int nb) {
        *(half8*)&klds[nb][srow][scol] = sK;
        *(half8*)&vlds[nb][srow][scol] = sV;
    };

    if (lo < hi) { gload(lo); swrite(0); }
    __syncthreads();

    const int qrow_min = q0 + rf * 16;        // this wave's smallest q row

    int cur = 0;
    for (int tl = lo; tl < hi; ++tl) {
        if (tl + 1 < hi) gload(tl + 1);       // issue next tile early

        const int kv0 = tl * 64 + kvh * 32;
        __builtin_amdgcn_s_setprio(1);
        f32x4 s[2];
#pragma unroll
        for (int h = 0; h < 2; h++) {
            const int keyl = kvh * 32 + 16 * h + (lane & 15);
            f32x4 a = f32x4{0, 0, 0, 0};
            a = mfma32(*(const half8*)&klds[cur][keyl][(lane >> 4) * 8], bq0, a);
            a = mfma32(*(const half8*)&klds[cur][keyl][32 + (lane >> 4) * 8], bq1, a);
            s[h] = a;
        }
        __builtin_amdgcn_s_setprio(0);

        float tv[8];
        if (kv0 + 31 <= qrow_min) {
            // interior tile for this wave: no masking needed (wave-uniform)
#pragma unroll
            for (int h = 0; h < 2; h++)
#pragma unroll
                for (int r = 0; r < 4; r++) tv[h * 4 + r] = s[h][r];
        } else {
            const int qrow = q0 + rf * 16 + (lane & 15);
            const int kb0  = kv0 + (lane >> 4) * 4;
#pragma unroll
            for (int h = 0; h < 2; h++)
#pragma unroll
                for (int r = 0; r < 4; r++)
                    tv[h * 4 + r] = (kb0 + 16 * h + r <= qrow) ? s[h][r] : NEG_BIG;
        }

        float mt = tv[0];
#pragma unroll
        for (int i = 1; i < 8; i++) mt = fmaxf(mt, tv[i]);
        mt = fmaxf(mt, __shfl_xor(mt, 16));
        mt = fmaxf(mt, __shfl_xor(mt, 32));

        if (!__all(mt <= m_r + DEFER_THR)) {  // defer-max rescale
            const float mn = fmaxf(m_r, mt);
            const float corr = exp2f(m_r - mn);
            m_r = mn;
            l_r *= corr;
            float corrB[4];
#pragma unroll
            for (int r = 0; r < 4; r++) corrB[r] = __shfl(corr, (lane >> 4) * 4 + r);
#pragma unroll
            for (int c = 0; c < 4; c++)
#pragma unroll
                for (int r = 0; r < 4; r++) o[c][r] *= corrB[r];
        }

        float p[8], rs = 0.f;
#pragma unroll
        for (int i = 0; i < 8; i++) { p[i] = exp2f(tv[i] - m_r); rs += p[i]; }
        rs += __shfl_xor(rs, 16);
        rs += __shfl_xor(rs, 32);
        l_r += rs;

        half4 pa[2];
#pragma unroll
        for (int h = 0; h < 2; h++)
#pragma unroll
            for (int r = 0; r < 4; r++) pa[h][r] = (_Float16)p[h * 4 + r];
        __builtin_amdgcn_s_setprio(1);
#pragma unroll
        for (int c = 0; c < 4; c++) {
#pragma unroll
            for (int h = 0; h < 2; h++) {
                const half4 vf = *(const half4*)&vlds[cur][16 * c + (lane & 15)]
                                                    [kvh * 32 + 16 * h + (lane >> 4) * 4];
                o[c] = mfma16(pa[h], vf, o[c]);
            }
        }
        __builtin_amdgcn_s_setprio(0);

        if (tl + 1 < hi) swrite(cur ^ 1);     // write OTHER buffer (race-free)
        __syncthreads();                      // single barrier per tile
        cur ^= 1;
    }

    // ---- pairwise (kv-half) merge, write block partial ----
    if (lane < 16) { mbuf[w * 16 + lane] = m_r; lbuf[w * 16 + lane] = l_r; }
#pragma unroll
    for (int c = 0; c < 4; c++)
#pragma unroll
        for (int r = 0; r < 4; r++)
            obuf[w][(lane >> 4) * 4 + r][16 * c + (lane & 15)] = o[c][r];
    __syncthreads();

    if (t < 256) {
        const int row16 = t >> 4, cb = (t & 15) * 4;
#pragma unroll
        for (int rf2 = 0; rf2 < 4; rf2++) {
            const int w0 = rf2 * 2, w1 = w0 + 1;
            const float m0v = mbuf[w0 * 16 + row16], m1v = mbuf[w1 * 16 + row16];
            const float M = fmaxf(m0v, m1v);
            const float e0 = exp2f(m0v - M), e1 = exp2f(m1v - M);
            const float L = lbuf[w0 * 16 + row16] * e0 + lbuf[w1 * 16 + row16] * e1;
            const f32x4 o0 = *(const f32x4*)&obuf[w0][row16][cb];
            const f32x4 o1 = *(const f32x4*)&obuf[w1][row16][cb];
            half4 hv;
#pragma unroll
            for (int jj = 0; jj < 4; jj++) hv[jj] = (_Float16)(o0[jj] * e0 + o1[jj] * e1);
            const size_t idx = (size_t)(qq * NB + b) * S_LEN + q0 + rf2 * 16 + row16;
            *(half4*)(po + idx * HD + cb) = hv;
            if ((t & 15) == 0) { pm[idx] = M; pl[idx] = L; }
        }
    }
}

// ---------------------------------------------------------------------------
// merge_kernel: combine the KVSPLIT partials per row.  grid (128, 4) x 256.
// ---------------------------------------------------------------------------
__global__ __launch_bounds__(256) void merge_kernel(
    const _Float16* __restrict__ po, const float* __restrict__ pm,
    const float* __restrict__ pl, float* __restrict__ out)
{
    const int b = blockIdx.y;
    const int row = blockIdx.x * 16 + (threadIdx.x >> 4);
    const int cb = (threadIdx.x & 15) * 4;

    float mv[KVSPLIT];
    float M = NEG_BIG;
#pragma unroll
    for (int qq = 0; qq < KVSPLIT; qq++) {
        mv[qq] = pm[(size_t)(qq * NB + b) * S_LEN + row];
        M = fmaxf(M, mv[qq]);
    }
    float L = 0.f;
    f32x4 acc = f32x4{0, 0, 0, 0};
#pragma unroll
    for (int qq = 0; qq < KVSPLIT; qq++) {
        const size_t idx = (size_t)(qq * NB + b) * S_LEN + row;
        const float e = exp2f(mv[qq] - M);
        L += pl[idx] * e;
        const half4 ov = *(const half4*)(po + idx * HD + cb);
#pragma unroll
        for (int jj = 0; jj < 4; jj++) acc[jj] += (float)ov[jj] * e;
    }
    const float inv = 1.0f / L;
    f32x4 res;
#pragma unroll
    for (int jj = 0; jj < 4; jj++) res[jj] = acc[jj] * inv;
    *(f32x4*)(out + ((size_t)b * S_LEN + row) * HD + cb) = res;
}

extern "C" void kernel_launch(void* const* d_in, const int* in_sizes, int n_in,
                              void* d_out, int out_size, void* d_ws, size_t ws_size,
                              hipStream_t stream) {
    const float* x  = (const float*)d_in[0];
    const float* Wq = (const float*)d_in[1];
    const float* bq = (const float*)d_in[2];
    const float* Wk = (const float*)d_in[3];
    const float* bk = (const float*)d_in[4];
    const float* Wv = (const float*)d_in[5];
    const float* bv = (const float*)d_in[6];
    float* out = (float*)d_out;

    _Float16* ws = (_Float16*)d_ws;
    const size_t nW = (size_t)192 * EMB;     // 196608 (12 frags x 16384)
    const size_t n  = (size_t)NROW * HD;     // 524288
    _Float16* wt_frag = ws;
    _Float16* qsb = wt_frag + nW;
    _Float16* khb = qsb + n;
    _Float16* vtb = khb + n;
    _Float16* po = vtb + n;                                // [4][4][2048][64] fp16
    float* pm = (float*)(po + (size_t)KVSPLIT * NB * S_LEN * HD);  // [4][4][2048]
    float* pl = pm + (size_t)KVSPLIT * NB * S_LEN;

    prep_w<<<48, 256, 0, stream>>>(Wq, Wk, Wv, wt_frag);
    proj_kernel<<<NROW / 32, 768, 0, stream>>>(
        x, wt_frag, bq, bk, bv, qsb, khb, vtb);
    attn_kernel<<<32 * NB * KVSPLIT, 512, 0, stream>>>(qsb, khb, vtb, po, pm, pl);
    merge_kernel<<<dim3(S_LEN / 16, NB), 256, 0, stream>>>(po, pm, pl, out);
}

// Round 14
// 36.351 us; speedup vs baseline: 4.6024x; 1.0132x over previous
//
#include <hip/hip_runtime.h>
#include <math.h>

#define S_LEN 2048
#define NB 4
#define EMB 1024
#define HD 64
#define NROW (NB * S_LEN)
#define NEG_BIG -3.0e38f
#define SC 11.5415603f /* 8 * log2(e) */
#define DEFER_THR 3.0f
#define KVSPLIT 4

typedef _Float16 half8 __attribute__((ext_vector_type(8)));
typedef _Float16 half4 __attribute__((ext_vector_type(4)));
typedef float f32x4 __attribute__((ext_vector_type(4)));

static __device__ __forceinline__ f32x4 mfma32(half8 a, half8 b, f32x4 c) {
    return __builtin_amdgcn_mfma_f32_16x16x32_f16(a, b, c, 0, 0, 0);
}
// K=16 shape: A-frag k-index = (lane>>4)*4 + i (validated empirically R4-R13).
static __device__ __forceinline__ f32x4 mfma16(half4 a, half4 b, f32x4 c) {
    return __builtin_amdgcn_mfma_f32_16x16x16f16(a, b, c, 0, 0, 0);
}

// ---------------------------------------------------------------------------
// prep_w: W [1024][64] fp32 -> W^T fp16 in MFMA-FRAGMENT-LINEAR layout:
//   addr = f*16384 + c32*512 + lane*8 + e
//   value = W^T[f*16 + (lane&15)][c32*32 + (lane>>4)*8 + e]
// grid 48 (3 mats x 16 k-chunks of 64), 256 thr, coalesced in.  (R9 exact)
// ---------------------------------------------------------------------------
__global__ __launch_bounds__(256) void prep_w(
    const float* __restrict__ Wq, const float* __restrict__ Wk,
    const float* __restrict__ Wv, _Float16* __restrict__ wt_frag)
{
    const int g  = blockIdx.x >> 4;
    const int kc = blockIdx.x & 15;          // 64-k chunk
    const int k0 = kc * 64;
    const float* W = (g == 0) ? Wq : (g == 1) ? Wk : Wv;

    __shared__ float tile[64][68];
    const int t = threadIdx.x;
    {
        const int kk = t >> 2, cb = (t & 3) * 16;
#pragma unroll
        for (int i = 0; i < 4; i++)
            *(f32x4*)&tile[kk][cb + 4 * i] =
                *(const f32x4*)(W + (size_t)(k0 + kk) * HD + cb + 4 * i);
    }
    __syncthreads();

    const int c4 = t >> 6, l = t & 63;
    const int col = c4 * 16 + (l & 15);
    const int krow = (l >> 4) * 8;
#pragma unroll
    for (int sub = 0; sub < 2; sub++) {
        half8 hv;
#pragma unroll
        for (int e = 0; e < 8; e++)
            hv[e] = (_Float16)tile[sub * 32 + krow + e][col];
        const size_t addr = (size_t)(g * 4 + c4) * 16384 +
                            (size_t)(kc * 2 + sub) * 512 + (size_t)l * 8;
        *(half8*)(wt_frag + addr) = hv;
    }
}

// ---------------------------------------------------------------------------
// proj_kernel: fused q,k,v projection.  256 blocks x 768 thr (12 waves).
// x strip (32x1024) staged to LDS ONCE; W^T streamed per-wave from global in
// fragment-linear layout (contiguous 1KB/load), 4-deep register prefetch.
// K-loop BARRIER-FREE.  (R9 exact -- near HBM floor)
// ---------------------------------------------------------------------------
__global__ __launch_bounds__(768) void proj_kernel(
    const float* __restrict__ x, const _Float16* __restrict__ wt_frag,
    const float* __restrict__ bq, const float* __restrict__ bk,
    const float* __restrict__ bv,
    _Float16* __restrict__ qs, _Float16* __restrict__ kh_,
    _Float16* __restrict__ vt)
{
    const int m0 = blockIdx.x * 32;
    const int t = threadIdx.x, lane = t & 63, w = t >> 6;   // w 0..11

    __shared__ __align__(16) _Float16 xs[32][1032];

    // ---- stage x strip once: 32 rows x 1024 f32 -> fp16 ----
    for (int i = t; i < 4096; i += 768) {
        const int row = i >> 7, off = (i & 127) * 8;
        const float* xp = x + (size_t)(m0 + row) * EMB + off;
        const f32x4 v0 = *(const f32x4*)xp;
        const f32x4 v1 = *(const f32x4*)(xp + 4);
        half8 h;
#pragma unroll
        for (int jj = 0; jj < 4; jj++) {
            h[jj]     = (_Float16)v0[jj];
            h[4 + jj] = (_Float16)v1[jj];
        }
        *(half8*)&xs[row][off] = h;
    }

    const int f = w;
    const int row0 = lane & 15, kq = lane >> 4;
    const _Float16* wp = wt_frag + (size_t)f * 16384 + (size_t)lane * 8;

    half8 wbuf[4];
#pragma unroll
    for (int c = 0; c < 4; c++) wbuf[c] = *(const half8*)(wp + (size_t)c * 512);

    __syncthreads();

    f32x4 acc0 = f32x4{0, 0, 0, 0}, acc1 = f32x4{0, 0, 0, 0};

#pragma unroll
    for (int c = 0; c < 32; ++c) {
        const half8 ax0 = *(const half8*)&xs[row0][c * 32 + kq * 8];
        const half8 ax1 = *(const half8*)&xs[16 + row0][c * 32 + kq * 8];
        const half8 bw = wbuf[c & 3];
        acc0 = mfma32(ax0, bw, acc0);
        acc1 = mfma32(ax1, bw, acc1);
        if (c + 4 < 32) wbuf[c & 3] = *(const half8*)(wp + (size_t)(c + 4) * 512);
    }

    // ---- epilogue ----
    const int mat = f >> 2, c4 = f & 3;
    const int mcol = c4 * 16 + (lane & 15);
    const float bb = ((mat == 0) ? bq : (mat == 1) ? bk : bv)[mcol];
#pragma unroll
    for (int rh = 0; rh < 2; rh++) {
        const f32x4 acc = rh ? acc1 : acc0;
        const int grow0 = m0 + rh * 16 + kq * 4;
        if (mat == 0) {
#pragma unroll
            for (int r = 0; r < 4; r++)
                qs[(size_t)(grow0 + r) * HD + mcol] = (_Float16)((acc[r] + bb) * SC);
        } else if (mat == 1) {
#pragma unroll
            for (int r = 0; r < 4; r++)
                kh_[(size_t)(grow0 + r) * HD + mcol] = (_Float16)(acc[r] + bb);
        } else {
            half4 hv;
#pragma unroll
            for (int r = 0; r < 4; r++) hv[r] = (_Float16)(acc[r] + bb);
            const int bidx = grow0 >> 11, sr = grow0 & (S_LEN - 1);
            *(half4*)(vt + ((size_t)bidx * HD + mcol) * S_LEN + sr) = hv;
        }
    }
}

// ---------------------------------------------------------------------------
// attn_kernel: causal flash attention, swapped-QK, DOUBLE-BUFFERED LDS K/V
// tiles -> ONE barrier per tile-step.  512 blocks (32 q-tiles of 64 x
// 4 batch x KVSPLIT=4) x 512 thr.
// NEW vs R13: __launch_bounds__(512, 6) -> VGPR cap 85 -> 3 blocks/CU
// (24 waves/CU, +50% TLP on this latency-bound kernel).
// ---------------------------------------------------------------------------
__global__ __launch_bounds__(512, 6) void attn_kernel(
    const _Float16* __restrict__ qs, const _Float16* __restrict__ kh_,
    const _Float16* __restrict__ vt,
    _Float16* __restrict__ po, float* __restrict__ pm, float* __restrict__ pl)
{
    const int id = blockIdx.x;
    const int qq = id & 3;
    const int b  = (id >> 2) & 3;
    const int qt = 31 - (id >> 4);            // biggest q-tiles first
    const int q0 = qt * 64;
    const int t = threadIdx.x, lane = t & 63, w = t >> 6;
    const int rf = w >> 1, kvh = w & 1;

    __shared__ __align__(16) unsigned char smem[37888];
    _Float16 (*klds)[64][72] = (_Float16(*)[64][72])smem;          // [2][64][72]
    _Float16 (*vlds)[64][72] = (_Float16(*)[64][72])(smem + 18432);// [2][64][72]
    float (*obuf)[16][68] = (float(*)[16][68])smem;                // alias, post-loop
    float* mbuf = (float*)(smem + 36864);                          // [8][16]
    float* lbuf = (float*)(smem + 36864 + 512);                    // [8][16]

    const size_t rowq = ((size_t)b * S_LEN + q0 + rf * 16 + (lane & 15)) * HD + (lane >> 4) * 8;
    const half8 bq0 = *(const half8*)(qs + rowq);
    const half8 bq1 = *(const half8*)(qs + rowq + 32);

    f32x4 o[4];
#pragma unroll
    for (int c = 0; c < 4; c++) o[c] = f32x4{0, 0, 0, 0};
    float m_r = NEG_BIG, l_r = 0.f;

    const int nt = qt + 1;
    const int lo = (nt * qq) >> 2, hi = (nt * (qq + 1)) >> 2;

    const size_t kbase = (size_t)b * S_LEN * HD;
    const size_t vbase = (size_t)b * HD * S_LEN;
    const int srow = t >> 3, scol = (t & 7) * 8;

    half8 sK, sV;
    auto gload = [&](int tl) {
        sK = *(const half8*)(kh_ + kbase + (size_t)(tl * 64 + srow) * HD + scol);
        sV = *(const half8*)(vt + vbase + (size_t)srow * S_LEN + tl * 64 + scol);
    };
    auto swrite = [&](int nb) {
        *(half8*)&klds[nb][srow][scol] = sK;
        *(half8*)&vlds[nb][srow][scol] = sV;
    };

    if (lo < hi) { gload(lo); swrite(0); }
    __syncthreads();

    const int qrow_min = q0 + rf * 16;        // this wave's smallest q row

    int cur = 0;
    for (int tl = lo; tl < hi; ++tl) {
        if (tl + 1 < hi) gload(tl + 1);       // issue next tile early

        const int kv0 = tl * 64 + kvh * 32;
        __builtin_amdgcn_s_setprio(1);
        f32x4 s[2];
#pragma unroll
        for (int h = 0; h < 2; h++) {
            const int keyl = kvh * 32 + 16 * h + (lane & 15);
            f32x4 a = f32x4{0, 0, 0, 0};
            a = mfma32(*(const half8*)&klds[cur][keyl][(lane >> 4) * 8], bq0, a);
            a = mfma32(*(const half8*)&klds[cur][keyl][32 + (lane >> 4) * 8], bq1, a);
            s[h] = a;
        }
        __builtin_amdgcn_s_setprio(0);

        float tv[8];
        if (kv0 + 31 <= qrow_min) {
            // interior tile for this wave: no masking needed (wave-uniform)
#pragma unroll
            for (int h = 0; h < 2; h++)
#pragma unroll
                for (int r = 0; r < 4; r++) tv[h * 4 + r] = s[h][r];
        } else {
            const int qrow = q0 + rf * 16 + (lane & 15);
            const int kb0  = kv0 + (lane >> 4) * 4;
#pragma unroll
            for (int h = 0; h < 2; h++)
#pragma unroll
                for (int r = 0; r < 4; r++)
                    tv[h * 4 + r] = (kb0 + 16 * h + r <= qrow) ? s[h][r] : NEG_BIG;
        }

        float mt = tv[0];
#pragma unroll
        for (int i = 1; i < 8; i++) mt = fmaxf(mt, tv[i]);
        mt = fmaxf(mt, __shfl_xor(mt, 16));
        mt = fmaxf(mt, __shfl_xor(mt, 32));

        if (!__all(mt <= m_r + DEFER_THR)) {  // defer-max rescale
            const float mn = fmaxf(m_r, mt);
            const float corr = exp2f(m_r - mn);
            m_r = mn;
            l_r *= corr;
            float corrB[4];
#pragma unroll
            for (int r = 0; r < 4; r++) corrB[r] = __shfl(corr, (lane >> 4) * 4 + r);
#pragma unroll
            for (int c = 0; c < 4; c++)
#pragma unroll
                for (int r = 0; r < 4; r++) o[c][r] *= corrB[r];
        }

        float p[8], rs = 0.f;
#pragma unroll
        for (int i = 0; i < 8; i++) { p[i] = exp2f(tv[i] - m_r); rs += p[i]; }
        rs += __shfl_xor(rs, 16);
        rs += __shfl_xor(rs, 32);
        l_r += rs;

        half4 pa[2];
#pragma unroll
        for (int h = 0; h < 2; h++)
#pragma unroll
            for (int r = 0; r < 4; r++) pa[h][r] = (_Float16)p[h * 4 + r];
        __builtin_amdgcn_s_setprio(1);
#pragma unroll
        for (int c = 0; c < 4; c++) {
#pragma unroll
            for (int h = 0; h < 2; h++) {
                const half4 vf = *(const half4*)&vlds[cur][16 * c + (lane & 15)]
                                                    [kvh * 32 + 16 * h + (lane >> 4) * 4];
                o[c] = mfma16(pa[h], vf, o[c]);
            }
        }
        __builtin_amdgcn_s_setprio(0);

        if (tl + 1 < hi) swrite(cur ^ 1);     // write OTHER buffer (race-free)
        __syncthreads();                      // single barrier per tile
        cur ^= 1;
    }

    // ---- pairwise (kv-half) merge, write block partial ----
    if (lane < 16) { mbuf[w * 16 + lane] = m_r; lbuf[w * 16 + lane] = l_r; }
#pragma unroll
    for (int c = 0; c < 4; c++)
#pragma unroll
        for (int r = 0; r < 4; r++)
            obuf[w][(lane >> 4) * 4 + r][16 * c + (lane & 15)] = o[c][r];
    __syncthreads();

    if (t < 256) {
        const int row16 = t >> 4, cb = (t & 15) * 4;
#pragma unroll
        for (int rf2 = 0; rf2 < 4; rf2++) {
            const int w0 = rf2 * 2, w1 = w0 + 1;
            const float m0v = mbuf[w0 * 16 + row16], m1v = mbuf[w1 * 16 + row16];
            const float M = fmaxf(m0v, m1v);
            const float e0 = exp2f(m0v - M), e1 = exp2f(m1v - M);
            const float L = lbuf[w0 * 16 + row16] * e0 + lbuf[w1 * 16 + row16] * e1;
            const f32x4 o0 = *(const f32x4*)&obuf[w0][row16][cb];
            const f32x4 o1 = *(const f32x4*)&obuf[w1][row16][cb];
            half4 hv;
#pragma unroll
            for (int jj = 0; jj < 4; jj++) hv[jj] = (_Float16)(o0[jj] * e0 + o1[jj] * e1);
            const size_t idx = (size_t)(qq * NB + b) * S_LEN + q0 + rf2 * 16 + row16;
            *(half4*)(po + idx * HD + cb) = hv;
            if ((t & 15) == 0) { pm[idx] = M; pl[idx] = L; }
        }
    }
}

// ---------------------------------------------------------------------------
// merge_kernel: combine the KVSPLIT partials per row.  grid (128, 4) x 256.
// ---------------------------------------------------------------------------
__global__ __launch_bounds__(256) void merge_kernel(
    const _Float16* __restrict__ po, const float* __restrict__ pm,
    const float* __restrict__ pl, float* __restrict__ out)
{
    const int b = blockIdx.y;
    const int row = blockIdx.x * 16 + (threadIdx.x >> 4);
    const int cb = (threadIdx.x & 15) * 4;

    float mv[KVSPLIT];
    float M = NEG_BIG;
#pragma unroll
    for (int qq = 0; qq < KVSPLIT; qq++) {
        mv[qq] = pm[(size_t)(qq * NB + b) * S_LEN + row];
        M = fmaxf(M, mv[qq]);
    }
    float L = 0.f;
    f32x4 acc = f32x4{0, 0, 0, 0};
#pragma unroll
    for (int qq = 0; qq < KVSPLIT; qq++) {
        const size_t idx = (size_t)(qq * NB + b) * S_LEN + row;
        const float e = exp2f(mv[qq] - M);
        L += pl[idx] * e;
        const half4 ov = *(const half4*)(po + idx * HD + cb);
#pragma unroll
        for (int jj = 0; jj < 4; jj++) acc[jj] += (float)ov[jj] * e;
    }
    const float inv = 1.0f / L;
    f32x4 res;
#pragma unroll
    for (int jj = 0; jj < 4; jj++) res[jj] = acc[jj] * inv;
    *(f32x4*)(out + ((size_t)b * S_LEN + row) * HD + cb) = res;
}

extern "C" void kernel_launch(void* const* d_in, const int* in_sizes, int n_in,
                              void* d_out, int out_size, void* d_ws, size_t ws_size,
                              hipStream_t stream) {
    const float* x  = (const float*)d_in[0];
    const float* Wq = (const float*)d_in[1];
    const float* bq = (const float*)d_in[2];
    const float* Wk = (const float*)d_in[3];
    const float* bk = (const float*)d_in[4];
    const float* Wv = (const float*)d_in[5];
    const float* bv = (const float*)d_in[6];
    float* out = (float*)d_out;

    _Float16* ws = (_Float16*)d_ws;
    const size_t nW = (size_t)192 * EMB;     // 196608 (12 frags x 16384)
    const size_t n  = (size_t)NROW * HD;     // 524288
    _Float16* wt_frag = ws;
    _Float16* qsb = wt_frag + nW;
    _Float16* khb = qsb + n;
    _Float16* vtb = khb + n;
    _Float16* po = vtb + n;                                // [4][4][2048][64] fp16
    float* pm = (float*)(po + (size_t)KVSPLIT * NB * S_LEN * HD);  // [4][4][2048]
    float* pl = pm + (size_t)KVSPLIT * NB * S_LEN;

    prep_w<<<48, 256, 0, stream>>>(Wq, Wk, Wv, wt_frag);
    proj_kernel<<<NROW / 32, 768, 0, stream>>>(
        x, wt_frag, bq, bk, bv, qsb, khb, vtb);
    attn_kernel<<<32 * NB * KVSPLIT, 512, 0, stream>>>(qsb, khb, vtb, po, pm, pl);
    merge_kernel<<<dim3(S_LEN / 16, NB), 256, 0, stream>>>(po, pm, pl, out);
}